// Round 5
// baseline (229.547 us; speedup 1.0000x reference)
//
#include <hip/hip_runtime.h>
#include <hip/hip_bf16.h>
#include <math.h>

#define NEG_SLOPE 0.2f
typedef unsigned short u16;
typedef short bf16x8 __attribute__((ext_vector_type(8)));
typedef float f32x4 __attribute__((ext_vector_type(4)));

__device__ __forceinline__ float bfu2f(u16 u) { return __uint_as_float(((unsigned)u) << 16); }
__device__ __forceinline__ u16 f2bu(float v) { return __bfloat16_as_ushort(__float2bfloat16(v)); }

// ---------------- init ----------------
__global__ void init_kernel(int* deg, int* cursor, float* pooled, int N, int P) {
    int i = blockIdx.x * blockDim.x + threadIdx.x;
    if (i < N) { deg[i] = 0; cursor[i] = 0; }
    if (i < P) pooled[i] = 0.f;
}

// ---------------- CSR build ----------------
__global__ void count_kernel(const int* __restrict__ edst, int E, int N, int* deg) {
    int i = blockIdx.x * blockDim.x + threadIdx.x;
    int total = E + N;
    if (i >= total) return;
    int dn = (i < E) ? edst[i] : (i - E);
    atomicAdd(&deg[dn], 1);
}

__global__ void scan_kernel(const int* __restrict__ deg, int N, int* __restrict__ offsets) {
    __shared__ int part[257];
    int tid = threadIdx.x;
    int chunk = (N + 255) / 256;
    int begin = tid * chunk;
    int fin = begin + chunk; if (fin > N) fin = N; if (begin > N) begin = N;
    int sum = 0;
    for (int i = begin; i < fin; ++i) sum += deg[i];
    part[tid] = sum;
    __syncthreads();
    if (tid == 0) {
        int acc = 0;
        for (int t = 0; t < 256; ++t) { int v = part[t]; part[t] = acc; acc += v; }
        part[256] = acc;
    }
    __syncthreads();
    int acc = part[tid];
    for (int i = begin; i < fin; ++i) { offsets[i] = acc; acc += deg[i]; }
    if (tid == 255) offsets[N] = part[256];
}

// scatter writes srcg directly (slot -> source node id)
__global__ void scatter_kernel(const int* __restrict__ esrc, const int* __restrict__ edst,
                               int E, int N, const int* __restrict__ offsets,
                               int* cursor, int* __restrict__ srcg) {
    int i = blockIdx.x * blockDim.x + threadIdx.x;
    int total = E + N;
    if (i >= total) return;
    int sn, dn;
    if (i < E) { sn = esrc[i]; dn = edst[i]; } else { sn = i - E; dn = i - E; }
    int pos = atomicAdd(&cursor[dn], 1);
    srcg[offsets[dn] + pos] = sn;
}

// ---------------- fused conversions: x->bf16, W1/W2/W3 -> bf16 transposed ----------------
__global__ void cvt_kernel(const float* __restrict__ x, u16* __restrict__ xb, int nx,
                           const float* __restrict__ W1, u16* __restrict__ Wt1, int K1, int F1,
                           const float* __restrict__ W2, u16* __restrict__ Wt2, int K2, int F2,
                           const float* __restrict__ W3, u16* __restrict__ Wt3, int K3, int F3,
                           int bs1, int bs2, int bs3) {
    int bid = blockIdx.x, tid = threadIdx.x;
    if (bid < bs1) {
        int i = bid * 256 + tid;
        if (i < nx) xb[i] = f2bu(x[i]);
    } else if (bid < bs2) {
        int i = (bid - bs1) * 256 + tid;
        if (i < K1 * F1) { int k = i % K1, f = i / K1; Wt1[i] = f2bu(W1[(size_t)k * F1 + f]); }
    } else if (bid < bs3) {
        int i = (bid - bs2) * 256 + tid;
        if (i < K2 * F2) { int k = i % K2, f = i / K2; Wt2[i] = f2bu(W2[(size_t)k * F2 + f]); }
    } else {
        int i = (bid - bs3) * 256 + tid;
        if (i < K3 * F3) { int k = i % K3, f = i / K3; Wt3[i] = f2bu(W3[(size_t)k * F3 + f]); }
    }
}

// ---------------- ws[k] = sum_f W[k][f]*a_s[f]; wd likewise (layers 2,3) ----------------
__global__ void ws_kernel(const float* __restrict__ W2, const float* __restrict__ as2,
                          const float* __restrict__ ad2, int K2, int F2,
                          const float* __restrict__ W3, const float* __restrict__ as3,
                          const float* __restrict__ ad3, int K3, int F3,
                          float* __restrict__ ws2, float* __restrict__ wd2,
                          float* __restrict__ ws3, float* __restrict__ wd3) {
    int w = (blockIdx.x * blockDim.x + threadIdx.x) >> 6;
    int lane = threadIdx.x & 63;
    const float *W, *va, *vd; float *os, *od; int F, row;
    if (w < K2) { W = W2; va = as2; vd = ad2; F = F2; row = w; os = ws2; od = wd2; }
    else if (w < K2 + K3) { W = W3; va = as3; vd = ad3; F = F3; row = w - K2; os = ws3; od = wd3; }
    else return;
    const float* wr = W + (size_t)row * F;
    float ss = 0.f, dd = 0.f;
    for (int f = lane; f < F; f += 64) { float wv = wr[f]; ss += wv * va[f]; dd += wv * vd[f]; }
    for (int off = 32; off; off >>= 1) { ss += __shfl_xor(ss, off); dd += __shfl_xor(dd, off); }
    if (lane == 0) { os[row] = ss; od[row] = dd; }
}

// ---------------- MFMA GEMM: C[M][F] = A[M][K] @ Wt[F][K]^T ----------------
// SD_EPI: also emit s[n]=h[n].as, d[n]=h[n].ad (requires grid.y==1, MR==1)
// POOL:   skip C store; atomicMax relu(acc+bias) into pooled[col]
template <int K, int MR, bool BIASRELU, bool SD_EPI, bool POOL>
__global__ __launch_bounds__(256) void mfma_gemm(const u16* __restrict__ A,
                                                 const u16* __restrict__ Wt,
                                                 u16* __restrict__ C,
                                                 const float* __restrict__ bias,
                                                 int M, int F,
                                                 const float* __restrict__ asv,
                                                 const float* __restrict__ adv,
                                                 float* __restrict__ s_out,
                                                 float* __restrict__ d_out,
                                                 float* __restrict__ pooled) {
    constexpr int NK = K / 32;
    int tid = threadIdx.x;
    int w = tid >> 6, l = tid & 63;
    int l15 = l & 15, q = l >> 4;
    int bm = blockIdx.x * (64 * MR);
    int bn = blockIdx.y * 64;
    int r0 = bm + w * (16 * MR);

    const u16* aptr[MR];
    int row[MR];
#pragma unroll
    for (int mr = 0; mr < MR; ++mr) {
        int r = r0 + mr * 16 + l15;
        row[mr] = r;
        int ar = (r < M) ? r : (M - 1);
        aptr[mr] = A + (size_t)ar * K + 8 * q;
    }
    const u16* bptr[4];
#pragma unroll
    for (int nt = 0; nt < 4; ++nt)
        bptr[nt] = Wt + (size_t)(bn + nt * 16 + l15) * K + 8 * q;

    f32x4 acc[MR][4];
#pragma unroll
    for (int mr = 0; mr < MR; ++mr)
#pragma unroll
        for (int nt = 0; nt < 4; ++nt) acc[mr][nt] = (f32x4){0.f, 0.f, 0.f, 0.f};

    bf16x8 a_cur[MR], b_cur[4], a_nxt[MR], b_nxt[4];
#pragma unroll
    for (int mr = 0; mr < MR; ++mr) a_cur[mr] = *(const bf16x8*)(aptr[mr]);
#pragma unroll
    for (int nt = 0; nt < 4; ++nt) b_cur[nt] = *(const bf16x8*)(bptr[nt]);

#pragma unroll
    for (int kk = 0; kk < NK; ++kk) {
        if (kk + 1 < NK) {
            int koff = (kk + 1) * 32;
#pragma unroll
            for (int mr = 0; mr < MR; ++mr) a_nxt[mr] = *(const bf16x8*)(aptr[mr] + koff);
#pragma unroll
            for (int nt = 0; nt < 4; ++nt) b_nxt[nt] = *(const bf16x8*)(bptr[nt] + koff);
        }
#pragma unroll
        for (int mr = 0; mr < MR; ++mr)
#pragma unroll
            for (int nt = 0; nt < 4; ++nt)
                acc[mr][nt] = __builtin_amdgcn_mfma_f32_16x16x32_bf16(b_cur[nt], a_cur[mr], acc[mr][nt], 0, 0, 0);
        if (kk + 1 < NK) {
#pragma unroll
            for (int mr = 0; mr < MR; ++mr) a_cur[mr] = a_nxt[mr];
#pragma unroll
            for (int nt = 0; nt < 4; ++nt) b_cur[nt] = b_nxt[nt];
        }
    }

    if constexpr (POOL) {
        float pmax[4][4];
#pragma unroll
        for (int nt = 0; nt < 4; ++nt)
#pragma unroll
            for (int r = 0; r < 4; ++r) pmax[nt][r] = 0.f;
#pragma unroll
        for (int mr = 0; mr < MR; ++mr) {
            if (row[mr] >= M) continue;
#pragma unroll
            for (int nt = 0; nt < 4; ++nt)
#pragma unroll
                for (int r = 0; r < 4; ++r) {
                    float v = acc[mr][nt][r];
                    if (BIASRELU) { v += bias[bn + nt * 16 + 4 * q + r]; v = fmaxf(v, 0.f); }
                    pmax[nt][r] = fmaxf(pmax[nt][r], v);
                }
        }
        // reduce over l15 within each q-group (cols independent of l15)
#pragma unroll
        for (int nt = 0; nt < 4; ++nt)
#pragma unroll
            for (int r = 0; r < 4; ++r) {
#pragma unroll
                for (int msk = 1; msk < 16; msk <<= 1)
                    pmax[nt][r] = fmaxf(pmax[nt][r], __shfl_xor(pmax[nt][r], msk));
                if (l15 == 0)
                    atomicMax((int*)&pooled[bn + nt * 16 + 4 * q + r], __float_as_int(pmax[nt][r]));
            }
        return;
    }

#pragma unroll
    for (int mr = 0; mr < MR; ++mr) {
        if (row[mr] >= M) continue;
#pragma unroll
        for (int nt = 0; nt < 4; ++nt) {
            int col = bn + nt * 16 + 4 * q;
            ushort4 st;
#pragma unroll
            for (int r = 0; r < 4; ++r) {
                float v = acc[mr][nt][r];
                if (BIASRELU) { v += bias[col + r]; v = fmaxf(v, 0.f); }
                ((u16*)&st)[r] = f2bu(v);
            }
            *(ushort4*)(C + (size_t)row[mr] * F + col) = st;
        }
    }

    if constexpr (SD_EPI) { // MR==1, grid.y==1, F==64: full row in 4 lanes (q varies)
        float ss = 0.f, dd = 0.f;
#pragma unroll
        for (int nt = 0; nt < 4; ++nt)
#pragma unroll
            for (int r = 0; r < 4; ++r) {
                int col = nt * 16 + 4 * q + r;
                float v = acc[0][nt][r];
                ss += v * asv[col];
                dd += v * adv[col];
            }
        ss += __shfl_xor(ss, 16); ss += __shfl_xor(ss, 32);
        dd += __shfl_xor(dd, 16); dd += __shfl_xor(dd, 32);
        if (q == 0 && row[0] < M) { s_out[row[0]] = ss; d_out[row[0]] = dd; }
    }
}

// ---------------- standalone sd (layer 3: s,d from a2) ----------------
__global__ void sd_kernel(const u16* __restrict__ h, const float* __restrict__ a_s,
                          const float* __restrict__ a_d, int N, int F,
                          float* __restrict__ s, float* __restrict__ d) {
    int wave = (blockIdx.x * blockDim.x + threadIdx.x) >> 6;
    int lane = threadIdx.x & 63;
    if (wave >= N) return;
    const u16* hrow = h + (size_t)wave * F;
    float ss = 0.f, dd = 0.f;
    for (int f = lane * 4; f < F; f += 256) {
        ushort4 u = *reinterpret_cast<const ushort4*>(hrow + f);
        float4 av = *reinterpret_cast<const float4*>(a_s + f);
        float4 dv = *reinterpret_cast<const float4*>(a_d + f);
        float h0 = bfu2f(u.x), h1 = bfu2f(u.y), h2 = bfu2f(u.z), h3 = bfu2f(u.w);
        ss += h0 * av.x + h1 * av.y + h2 * av.z + h3 * av.w;
        dd += h0 * dv.x + h1 * dv.y + h2 * dv.z + h3 * dv.w;
    }
    for (int off = 32; off; off >>= 1) { ss += __shfl_xor(ss, off); dd += __shfl_xor(dd, off); }
    if (lane == 0) { s[wave] = ss; d[wave] = dd; }
}

// ---------------- fused softmax + gather (block per node, 4-way edge split) ----------------
// SD_EPI (F==64 only): also emit s_out[n] = out_row . wsv, d_out[n] = out_row . wdv
template <int F, bool BIASRELU, bool SD_EPI>
__global__ __launch_bounds__(256) void agg_kernel(const u16* __restrict__ h,
                                                  const float* __restrict__ sv,
                                                  const float* __restrict__ dvec,
                                                  const int* __restrict__ srcg,
                                                  const int* __restrict__ offsets,
                                                  const float* __restrict__ bias,
                                                  u16* __restrict__ out,
                                                  const float* __restrict__ wsv,
                                                  const float* __restrict__ wdv,
                                                  float* __restrict__ s_out,
                                                  float* __restrict__ d_out) {
    constexpr int VPT = F / 64;
    __shared__ float red[3][F];
    int n = blockIdx.x;
    int w = threadIdx.x >> 6, lane = threadIdx.x & 63;
    int start = offsets[n], end = offsets[n + 1];
    float dval = dvec[n];
    // softmax scalars, computed redundantly per wave (no barrier needed)
    float lmax = -INFINITY;
    for (int j = start + lane; j < end; j += 64) {
        float v = sv[srcg[j]] + dval; v = (v >= 0.f) ? v : NEG_SLOPE * v;
        lmax = fmaxf(lmax, v);
    }
    for (int off = 32; off; off >>= 1) lmax = fmaxf(lmax, __shfl_xor(lmax, off));
    float ls = 0.f;
    for (int j = start + lane; j < end; j += 64) {
        float v = sv[srcg[j]] + dval; v = (v >= 0.f) ? v : NEG_SLOPE * v;
        ls += expf(v - lmax);
    }
    for (int off = 32; off; off >>= 1) ls += __shfl_xor(ls, off);
    float inv = 1.f / ls;
    // gather: wave w handles edges j = start+w, step 4
    float acc[VPT];
#pragma unroll
    for (int v = 0; v < VPT; ++v) acc[v] = 0.f;
    for (int j = start + w; j < end; j += 4) {
        int sn = srcg[j];
        float e = sv[sn] + dval; e = (e >= 0.f) ? e : NEG_SLOPE * e;
        float a = expf(e - lmax) * inv;
        const u16* hp = h + (size_t)sn * F + lane * VPT;
        if constexpr (VPT == 4) {
            ushort4 u = *(const ushort4*)hp;
            acc[0] += a * bfu2f(u.x); acc[1] += a * bfu2f(u.y);
            acc[2] += a * bfu2f(u.z); acc[3] += a * bfu2f(u.w);
        } else {
            acc[0] += a * bfu2f(*hp);
        }
    }
    if (w > 0) {
#pragma unroll
        for (int v = 0; v < VPT; ++v) red[w - 1][lane * VPT + v] = acc[v];
    }
    __syncthreads();
    if (w != 0) return;
    float res[VPT];
    if constexpr (VPT == 4) {
        ushort4 st;
#pragma unroll
        for (int v = 0; v < VPT; ++v) {
            float x = acc[v] + red[0][lane * 4 + v] + red[1][lane * 4 + v] + red[2][lane * 4 + v];
            if (BIASRELU) { x += bias[lane * 4 + v]; x = fmaxf(x, 0.f); }
            res[v] = x;
            ((u16*)&st)[v] = f2bu(x);
        }
        *(ushort4*)(out + (size_t)n * F + lane * 4) = st;
    } else {
        float x = acc[0] + red[0][lane] + red[1][lane] + red[2][lane];
        if (BIASRELU) { x += bias[lane]; x = fmaxf(x, 0.f); }
        res[0] = x;
        out[(size_t)n * F + lane] = f2bu(x);
    }
    if constexpr (SD_EPI) { // F==64
        float ss = res[0] * wsv[lane], dd = res[0] * wdv[lane];
        for (int off = 32; off; off >>= 1) { ss += __shfl_xor(ss, off); dd += __shfl_xor(dd, off); }
        if (lane == 0) { s_out[n] = ss; d_out[n] = dd; }
    }
}

// ---------------- dense head ----------------
__global__ void head1a_kernel(const float* __restrict__ pooled, const float* __restrict__ lw1,
                              float* __restrict__ part) {
    int j = blockIdx.x * 128 + threadIdx.x;
    int k0 = blockIdx.y * 64;
    float acc = 0.f;
#pragma unroll 8
    for (int k = k0; k < k0 + 64; ++k) acc += pooled[k] * lw1[(size_t)k * 512 + j];
    part[blockIdx.y * 512 + j] = acc;
}

__global__ void head1b_kernel(const float* __restrict__ part, const float* __restrict__ lb1,
                              float* __restrict__ z1) {
    int j = blockIdx.x * 128 + threadIdx.x;
    float acc = lb1[j];
#pragma unroll
    for (int t = 0; t < 16; ++t) acc += part[t * 512 + j];
    z1[j] = fmaxf(acc, 0.f);
}

__global__ void head2_kernel(const float* __restrict__ z1, const float* __restrict__ lw2,
                             const float* __restrict__ lb2, float* __restrict__ out) {
    __shared__ float z2[10];
    int tid = threadIdx.x;
    if (tid < 10) {
        float acc = lb2[tid];
        for (int k = 0; k < 512; ++k) acc += z1[k] * lw2[k * 10 + tid];
        z2[tid] = acc;
    }
    __syncthreads();
    if (tid == 0) {
        float m = z2[0];
        for (int j = 1; j < 10; ++j) m = fmaxf(m, z2[j]);
        float ssum = 0.f;
        for (int j = 0; j < 10; ++j) ssum += expf(z2[j] - m);
        float lse = m + logf(ssum);
        for (int j = 0; j < 10; ++j) out[j] = z2[j] - lse;
    }
}

extern "C" void kernel_launch(void* const* d_in, const int* in_sizes, int n_in,
                              void* d_out, int out_size, void* d_ws, size_t ws_size,
                              hipStream_t stream) {
    const float* x   = (const float*)d_in[0];
    const int* ei    = (const int*)d_in[1];
    const float* W1  = (const float*)d_in[3];
    const float* as1 = (const float*)d_in[4];
    const float* ad1 = (const float*)d_in[5];
    const float* b1  = (const float*)d_in[6];
    const float* W2  = (const float*)d_in[7];
    const float* as2 = (const float*)d_in[8];
    const float* ad2 = (const float*)d_in[9];
    const float* b2  = (const float*)d_in[10];
    const float* W3  = (const float*)d_in[11];
    const float* as3 = (const float*)d_in[12];
    const float* ad3 = (const float*)d_in[13];
    const float* b3  = (const float*)d_in[14];
    const float* lw1 = (const float*)d_in[15];
    const float* lb1 = (const float*)d_in[16];
    const float* lw2 = (const float*)d_in[17];
    const float* lb2 = (const float*)d_in[18];
    float* out = (float*)d_out;

    const int N = in_sizes[0] / 128;
    const int E = in_sizes[1] / 2;
    const int total = E + N;
    const int* esrc = ei;
    const int* edst = ei + E;

    // bump allocator on d_ws, 256B aligned
    char* base = (char*)d_ws;
    size_t off = 0;
    auto alloc = [&](size_t bytes) { void* p = base + off; off = (off + bytes + 255) & ~(size_t)255; return p; };
    u16* xb    = (u16*)alloc((size_t)N * 128 * 2);
    u16* h1    = (u16*)alloc((size_t)N * 64 * 2);
    u16* a1    = (u16*)alloc((size_t)N * 64 * 2);
    u16* agg2b = (u16*)alloc((size_t)N * 64 * 2);
    u16* a2    = (u16*)alloc((size_t)N * 256 * 2);
    u16* agg3b = (u16*)alloc((size_t)N * 256 * 2);
    u16* Wt1   = (u16*)alloc(128 * 64 * 2);
    u16* Wt2   = (u16*)alloc(64 * 256 * 2);
    u16* Wt3   = (u16*)alloc(256 * 1024 * 2);
    float* ws2 = (float*)alloc(64 * 4);
    float* wd2 = (float*)alloc(64 * 4);
    float* ws3 = (float*)alloc(256 * 4);
    float* wd3 = (float*)alloc(256 * 4);
    float* sbuf = (float*)alloc((size_t)N * 4);
    float* dbuf = (float*)alloc((size_t)N * 4);
    float* pooled = (float*)alloc(1024 * 4);
    float* z1     = (float*)alloc(512 * 4);
    float* hpart  = (float*)alloc(16 * 512 * 4);
    int* deg     = (int*)alloc((size_t)N * 4);
    int* cursor  = (int*)alloc((size_t)N * 4);
    int* offsets = (int*)alloc((size_t)(N + 1) * 4);
    int* srcg    = (int*)alloc((size_t)total * 4);

    const int TPB = 256;
    int gN = (N + TPB - 1) / TPB;
    int gE = (total + TPB - 1) / TPB;
    int gW = (N + 3) / 4;
    int gR64 = (N + 63) / 64;
    int gR128 = (N + 127) / 128;
    int gR256 = (N + 255) / 256;

    // CSR build
    init_kernel<<<gN, TPB, 0, stream>>>(deg, cursor, pooled, N, 1024);
    count_kernel<<<gE, TPB, 0, stream>>>(edst, E, N, deg);
    scan_kernel<<<1, TPB, 0, stream>>>(deg, N, offsets);
    scatter_kernel<<<gE, TPB, 0, stream>>>(esrc, edst, E, N, offsets, cursor, srcg);

    // conversions
    int nx = N * 128;
    int bs1 = (nx + 255) / 256;
    int bs2 = bs1 + (128 * 64 + 255) / 256;
    int bs3 = bs2 + (64 * 256 + 255) / 256;
    int gC = bs3 + (256 * 1024 + 255) / 256;
    cvt_kernel<<<gC, TPB, 0, stream>>>(x, xb, nx, W1, Wt1, 128, 64,
                                       W2, Wt2, 64, 256, W3, Wt3, 256, 1024,
                                       bs1, bs2, bs3);
    ws_kernel<<<(64 + 256 + 3) / 4, TPB, 0, stream>>>(W2, as2, ad2, 64, 256,
                                                      W3, as3, ad3, 256, 1024,
                                                      ws2, wd2, ws3, wd3);

    // ---- layer 1: gemm (+s1,d1 epilogue), fused agg (+s2,d2 epilogue on a1) ----
    mfma_gemm<128, 1, false, true, false><<<dim3(gR64, 1), TPB, 0, stream>>>(
        xb, Wt1, h1, nullptr, N, 64, as1, ad1, sbuf, dbuf, nullptr);
    agg_kernel<64, true, true><<<N, TPB, 0, stream>>>(
        h1, sbuf, dbuf, srcg, offsets, b1, a1, ws2, wd2, sbuf, dbuf);

    // ---- layer 2: fused agg on a1 -> gemm2 (bias+relu) -> a2 ----
    agg_kernel<64, false, false><<<N, TPB, 0, stream>>>(
        a1, sbuf, dbuf, srcg, offsets, nullptr, agg2b, nullptr, nullptr, nullptr, nullptr);
    mfma_gemm<64, 2, true, false, false><<<dim3(gR128, 4), TPB, 0, stream>>>(
        agg2b, Wt2, a2, b2, N, 256, nullptr, nullptr, nullptr, nullptr, nullptr);

    // ---- layer 3: sd3 on a2, fused agg -> gemm3 (bias+relu+maxpool, no C) ----
    sd_kernel<<<gW, TPB, 0, stream>>>(a2, ws3, wd3, N, 256, sbuf, dbuf);
    agg_kernel<256, false, false><<<N, TPB, 0, stream>>>(
        a2, sbuf, dbuf, srcg, offsets, nullptr, agg3b, nullptr, nullptr, nullptr, nullptr);
    mfma_gemm<256, 4, true, false, true><<<dim3(gR256, 16), TPB, 0, stream>>>(
        agg3b, Wt3, nullptr, b3, N, 1024, nullptr, nullptr, nullptr, nullptr, pooled);

    // ---- head ----
    head1a_kernel<<<dim3(4, 16), 128, 0, stream>>>(pooled, lw1, hpart);
    head1b_kernel<<<4, 128, 0, stream>>>(hpart, lb1, z1);
    head2_kernel<<<1, 64, 0, stream>>>(z1, lw2, lb2, out);
}